// Round 2
// baseline (627.192 us; speedup 1.0000x reference)
//
#include <hip/hip_runtime.h>
#include <stdint.h>

typedef unsigned short u16;
typedef __bf16 bf16x8 __attribute__((ext_vector_type(8)));
typedef float f32x4 __attribute__((ext_vector_type(4)));

#define AS1(p) ((const __attribute__((address_space(1))) void*)(p))
#define AS3(p) ((__attribute__((address_space(3))) void*)(p))

__device__ __forceinline__ float b2f(u16 v){
    union { unsigned u; float f; } x; x.u = ((unsigned)v) << 16; return x.f;
}
__device__ __forceinline__ u16 f2b(float f){
    union { float f; unsigned u; } x; x.f = f;
    unsigned r = x.u + 0x7FFFu + ((x.u >> 16) & 1u);
    return (u16)(r >> 16);
}

// ---------------- dtype probe: one block per input tensor ----------------
// flags[i] = 1 if tensor i is fp32, 0 if bf16. flags[15] = 0 (constant).
// Rule: view memory as u16 pairs (lo,hi). If data is really fp32, hi-as-bf16 has
// exponent field >=0xF0 or in [1,0x40] (|v|>=2^113 or <=2^-63 — impossible for our
// bounded tensors as true bf16); lo is ~uniform random (same test adds evidence).
// Exactly-representable fp32 (e.g. 1.0) gives (lo==0, hi!=0) for a majority of pairs.
__global__ __launch_bounds__(256) void probe_kernel(
    const u16* p0,const u16* p1,const u16* p2,const u16* p3,const u16* p4,
    const u16* p5,const u16* p6,const u16* p7,const u16* p8,const u16* p9,
    const u16* p10,const u16* p11,const u16* p12,
    int n0,int n1,int n2,int n3,int n4,int n5,int n6,int n7,int n8,int n9,
    int n10,int n11,int n12, int* flags)
{
    const u16* p; int n;
    switch (blockIdx.x) {
        case 0: p=p0; n=n0; break;   case 1: p=p1; n=n1; break;
        case 2: p=p2; n=n2; break;   case 3: p=p3; n=n3; break;
        case 4: p=p4; n=n4; break;   case 5: p=p5; n=n5; break;
        case 6: p=p6; n=n6; break;   case 7: p=p7; n=n7; break;
        case 8: p=p8; n=n8; break;   case 9: p=p9; n=n9; break;
        case 10: p=p10; n=n10; break; case 11: p=p11; n=n11; break;
        default: p=p12; n=n12; break;
    }
    int pairs = n >> 1; if (pairs > 2048) pairs = 2048;
    int strong = 0, znz = 0, tot = 0;
    for (int k = threadIdx.x; k < pairs; k += 256) {
        u16 lo = p[2*k], hi = p[2*k+1];
        int eh = (hi >> 7) & 0xFF;
        int el = (lo >> 7) & 0xFF;
        if (eh >= 0xF0 || (eh >= 1 && eh <= 0x40)) strong = 1;
        if (el >= 0xF0 || (el >= 1 && el <= 0x40)) strong = 1;
        if (lo == 0 && hi != 0) znz++;
        tot++;
    }
    __shared__ int ss, sz, st;
    if (threadIdx.x == 0) { ss = 0; sz = 0; st = 0; }
    __syncthreads();
    if (strong) atomicOr(&ss, 1);
    if (znz) atomicAdd(&sz, znz);
    atomicAdd(&st, tot);
    __syncthreads();
    if (threadIdx.x == 0) {
        flags[blockIdx.x] = (ss || (2 * sz > st)) ? 1 : 0;
        if (blockIdx.x == 0) flags[15] = 0;
    }
}

// ---------------- convert all weight/vector tensors to bf16 in ws ----------------
__global__ __launch_bounds__(256) void convert_kernel(
    const void* sWc, const void* sW2, const void* sW1,
    const void* sTa, const void* sBc, const void* sG1, const void* sB1l,
    const void* sTf, const void* sB1, const void* sB2, const void* sG2, const void* sB2l,
    u16* wbase, const int* flags)
{
    int b = blockIdx.x;
    const void* src; u16* dst; int n, fi, lb;
    if (b < 128)      { src=sWc;  dst=wbase+0;        n=262144;  fi=2;  lb=b; }
    else if (b < 640) { src=sW2;  dst=wbase+262144;   n=1048576; fi=9;  lb=b-128; }
    else if (b < 648) { src=sW1;  dst=wbase+1310720;  n=16384;   fi=7;  lb=b-640; }
    else {
        lb = 0;
        switch (b) {
            case 648: src=sTa;  dst=wbase+1327104; n=512;  fi=1;  break;
            case 649: src=sBc;  dst=wbase+1327616; n=512;  fi=3;  break;
            case 650: src=sG1;  dst=wbase+1328128; n=512;  fi=4;  break;
            case 651: src=sB1l; dst=wbase+1328640; n=512;  fi=5;  break;
            case 652: src=sTf;  dst=wbase+1329152; n=8;    fi=6;  break;
            case 653: src=sB1;  dst=wbase+1329216; n=2048; fi=8;  break;
            case 654: src=sB2;  dst=wbase+1331264; n=512;  fi=10; break;
            case 655: src=sG2;  dst=wbase+1331776; n=512;  fi=11; break;
            default:  src=sB2l; dst=wbase+1332288; n=512;  fi=12; break;
        }
    }
    int i = lb * 256 + threadIdx.x;
    if (i * 8 >= n) return;
    if (flags[fi]) {
        const float4* s = (const float4*)src;
        float4 a = s[i*2], c = s[i*2+1];
        union { uint4 v; u16 h[8]; } o;
        o.h[0]=f2b(a.x); o.h[1]=f2b(a.y); o.h[2]=f2b(a.z); o.h[3]=f2b(a.w);
        o.h[4]=f2b(c.x); o.h[5]=f2b(c.y); o.h[6]=f2b(c.z); o.h[7]=f2b(c.w);
        ((uint4*)dst)[i] = o.v;
    } else {
        ((uint4*)dst)[i] = ((const uint4*)src)[i];
    }
}

// ---------------- q[m,e] = cos(x[m,e] + theta_flat[e]) ----------------
__global__ __launch_bounds__(256) void qcos_kernel(const void* x,
        const u16* __restrict__ theta, u16* __restrict__ q, const int* flags)
{
    int i = blockIdx.x * 256 + threadIdx.x;   // 8 elems per thread
    float xv[8];
    if (flags[0]) {
        const float4* xf = (const float4*)x;
        float4 a = xf[i*2], c = xf[i*2+1];
        xv[0]=a.x; xv[1]=a.y; xv[2]=a.z; xv[3]=a.w;
        xv[4]=c.x; xv[5]=c.y; xv[6]=c.z; xv[7]=c.w;
    } else {
        union { uint4 v; u16 h[8]; } xb;
        xb.v = ((const uint4*)x)[i];
        #pragma unroll
        for (int j = 0; j < 8; j++) xv[j] = b2f(xb.h[j]);
    }
    union { uint4 v; u16 h[8]; } tb, ob;
    tb.v = *(const uint4*)(theta + ((i * 8) & 511));
    #pragma unroll
    for (int j = 0; j < 8; j++)
        ob.h[j] = f2b(__cosf(xv[j] + b2f(tb.h[j])));
    ((uint4*)q)[i] = ob.v;
}

// ------- GEMM: dst[m,n] = sum_k A[m,k]*Wt[n,k] + bias[n] + res[m,n] -------
// res dtype selected by rflag[0] (1=fp32, 0=bf16). m97 structure.
__global__ __launch_bounds__(256) void gemm_bias_res(
    const u16* __restrict__ A, const u16* __restrict__ Wt,
    const u16* __restrict__ bias, const void* __restrict__ res,
    u16* __restrict__ dst, int K, int N, const int* rflag)
{
    __shared__ __align__(16) u16 As[128 * 64];
    __shared__ __align__(16) u16 Bs[128 * 64];
    const int tid  = threadIdx.x;
    const int lane = tid & 63;
    const int w    = tid >> 6;
    const int m0 = blockIdx.x * 128;
    const int n0 = blockIdx.y * 128;
    const int srow = lane >> 3;
    const int scol = (lane & 7) * 8;
    const int wm = (w >> 1) * 64;
    const int wn = (w & 1) * 64;
    const int fr   = lane & 15;
    const int quad = lane >> 4;

    f32x4 acc[4][4];
    #pragma unroll
    for (int i = 0; i < 4; i++)
        #pragma unroll
        for (int j = 0; j < 4; j++)
            acc[i][j] = f32x4{0.f, 0.f, 0.f, 0.f};

    for (int kt = 0; kt < K; kt += 64) {
        __syncthreads();
        #pragma unroll
        for (int i = 0; i < 4; i++) {
            int c = w * 4 + i;
            int row = c * 8 + srow;
            __builtin_amdgcn_global_load_lds(
                AS1(A + (size_t)(m0 + row) * K + kt + scol),
                AS3(As + c * 512), 16, 0, 0);
        }
        #pragma unroll
        for (int i = 0; i < 4; i++) {
            int c = w * 4 + i;
            int row = c * 8 + srow;
            __builtin_amdgcn_global_load_lds(
                AS1(Wt + (size_t)(n0 + row) * K + kt + scol),
                AS3(Bs + c * 512), 16, 0, 0);
        }
        __syncthreads();
        #pragma unroll
        for (int kk = 0; kk < 2; kk++) {
            bf16x8 af[4], bfr[4];
            #pragma unroll
            for (int mi = 0; mi < 4; mi++)
                af[mi] = *(const bf16x8*)(As + (wm + mi * 16 + fr) * 64 + kk * 32 + quad * 8);
            #pragma unroll
            for (int ni = 0; ni < 4; ni++)
                bfr[ni] = *(const bf16x8*)(Bs + (wn + ni * 16 + fr) * 64 + kk * 32 + quad * 8);
            #pragma unroll
            for (int mi = 0; mi < 4; mi++)
                #pragma unroll
                for (int ni = 0; ni < 4; ni++)
                    acc[mi][ni] = __builtin_amdgcn_mfma_f32_16x16x32_bf16(
                        af[mi], bfr[ni], acc[mi][ni], 0, 0, 0);
        }
    }

    const int rf = rflag[0];
    #pragma unroll
    for (int mi = 0; mi < 4; mi++) {
        #pragma unroll
        for (int ni = 0; ni < 4; ni++) {
            int n = n0 + wn + ni * 16 + fr;
            float bn = b2f(bias[n]);
            #pragma unroll
            for (int r = 0; r < 4; r++) {
                int m = m0 + wm + mi * 16 + quad * 4 + r;
                float rv = rf ? ((const float*)res)[(size_t)m * N + n]
                              : b2f(((const u16*)res)[(size_t)m * N + n]);
                dst[(size_t)m * N + n] = f2b(acc[mi][ni][r] + bn + rv);
            }
        }
    }
}

// ------- x1 = LN(y1)*g+b; fq = cos(x1[:8]+th); h = relu(fq@W1^T + b1) -------
__global__ __launch_bounds__(256) void ln1_ffn1_kernel(
    const u16* __restrict__ y1, const u16* __restrict__ g, const u16* __restrict__ b,
    const u16* __restrict__ th_ffn, const u16* __restrict__ W1, const u16* __restrict__ b1,
    u16* __restrict__ x1, u16* __restrict__ h)
{
    const int m = blockIdx.x;
    const int t = threadIdx.x;
    __shared__ float xs[512];
    __shared__ float rsum[4], rsumsq[4];
    __shared__ float stats[2];

    unsigned pair = *(const unsigned*)(y1 + (size_t)m * 512 + t * 2);
    float v0 = b2f((u16)(pair & 0xffff)), v1 = b2f((u16)(pair >> 16));
    float s = v0 + v1, ss = v0 * v0 + v1 * v1;
    #pragma unroll
    for (int o = 32; o > 0; o >>= 1) { s += __shfl_down(s, o); ss += __shfl_down(ss, o); }
    if ((t & 63) == 0) { rsum[t >> 6] = s; rsumsq[t >> 6] = ss; }
    __syncthreads();
    if (t == 0) {
        float S  = rsum[0] + rsum[1] + rsum[2] + rsum[3];
        float SS = rsumsq[0] + rsumsq[1] + rsumsq[2] + rsumsq[3];
        float mu = S * (1.f / 512.f);
        float var = SS * (1.f / 512.f) - mu * mu;
        stats[0] = mu; stats[1] = rsqrtf(var + 1e-5f);
    }
    __syncthreads();
    float mu = stats[0], rs = stats[1];
    int e0 = t * 2;
    float xa = (v0 - mu) * rs * b2f(g[e0])     + b2f(b[e0]);
    float xb = (v1 - mu) * rs * b2f(g[e0 + 1]) + b2f(b[e0 + 1]);
    xs[e0] = xa; xs[e0 + 1] = xb;
    *(unsigned*)(x1 + (size_t)m * 512 + e0) =
        (unsigned)f2b(xa) | ((unsigned)f2b(xb) << 16);
    __syncthreads();

    float fq[8];
    #pragma unroll
    for (int j = 0; j < 8; j++) fq[j] = __cosf(xs[j] + b2f(th_ffn[j]));

    union { uint4 v; u16 s[8]; } hb;
    int f0 = t * 8;
    #pragma unroll
    for (int j = 0; j < 8; j++) {
        int f = f0 + j;
        union { uint4 v; u16 s[8]; } wb;
        wb.v = *(const uint4*)(W1 + f * 8);
        float a = b2f(b1[f]);
        #pragma unroll
        for (int k2 = 0; k2 < 8; k2++) a += fq[k2] * b2f(wb.s[k2]);
        hb.s[j] = f2b(fmaxf(a, 0.f));
    }
    *(uint4*)(h + (size_t)m * 2048 + f0) = hb.v;
}

// ---------------- out = LN(z)*g2+b2, output dtype per flags[0] ----------------
__global__ __launch_bounds__(256) void ln2_kernel(
    const u16* __restrict__ z, const u16* __restrict__ g, const u16* __restrict__ b,
    void* __restrict__ out, const int* flags)
{
    const int m = blockIdx.x;
    const int t = threadIdx.x;
    __shared__ float rsum[4], rsumsq[4];
    __shared__ float stats[2];

    unsigned pair = *(const unsigned*)(z + (size_t)m * 512 + t * 2);
    float v0 = b2f((u16)(pair & 0xffff)), v1 = b2f((u16)(pair >> 16));
    float s = v0 + v1, ss = v0 * v0 + v1 * v1;
    #pragma unroll
    for (int o = 32; o > 0; o >>= 1) { s += __shfl_down(s, o); ss += __shfl_down(ss, o); }
    if ((t & 63) == 0) { rsum[t >> 6] = s; rsumsq[t >> 6] = ss; }
    __syncthreads();
    if (t == 0) {
        float S  = rsum[0] + rsum[1] + rsum[2] + rsum[3];
        float SS = rsumsq[0] + rsumsq[1] + rsumsq[2] + rsumsq[3];
        float mu = S * (1.f / 512.f);
        float var = SS * (1.f / 512.f) - mu * mu;
        stats[0] = mu; stats[1] = rsqrtf(var + 1e-5f);
    }
    __syncthreads();
    float mu = stats[0], rs = stats[1];
    int e0 = t * 2;
    float xa = (v0 - mu) * rs * b2f(g[e0])     + b2f(b[e0]);
    float xb = (v1 - mu) * rs * b2f(g[e0 + 1]) + b2f(b[e0 + 1]);
    if (flags[0]) {
        float2 o; o.x = xa; o.y = xb;
        *(float2*)((float*)out + (size_t)m * 512 + e0) = o;
    } else {
        *(unsigned*)((u16*)out + (size_t)m * 512 + e0) =
            (unsigned)f2b(xa) | ((unsigned)f2b(xb) << 16);
    }
}

extern "C" void kernel_launch(void* const* d_in, const int* in_sizes, int n_in,
                              void* d_out, int out_size, void* d_ws, size_t ws_size,
                              hipStream_t stream)
{
    u16* ws16 = (u16*)d_ws;
    // ws layout (u16 elements), ~103.3 MB total:
    //   [0,        16777216)  q, later x1 (row-aliased)
    //   [16777216, 33554432)  y1, later z (row-aliased: z chunk overwrites consumed y1 rows)
    //   [33554432, 50331648)  h chunk buffer (8192 x 2048)
    //   [50331648, 51664448)  converted bf16 weights/vectors
    //   flags at elem 51665024 (16 ints)
    u16* q   = ws16;
    u16* x1  = ws16;
    u16* y1  = ws16 + 16777216;
    u16* z   = y1;
    u16* hb  = ws16 + 33554432;
    u16* W   = ws16 + 50331648;
    int* flags = (int*)(ws16 + 51665024);

    const u16* wWc  = W;
    const u16* wW2  = W + 262144;
    const u16* wW1  = W + 1310720;
    const u16* wTa  = W + 1327104;
    const u16* wBc  = W + 1327616;
    const u16* wG1  = W + 1328128;
    const u16* wB1l = W + 1328640;
    const u16* wTf  = W + 1329152;
    const u16* wB1  = W + 1329216;
    const u16* wB2  = W + 1331264;
    const u16* wG2  = W + 1331776;
    const u16* wB2l = W + 1332288;

    probe_kernel<<<13, 256, 0, stream>>>(
        (const u16*)d_in[0], (const u16*)d_in[1], (const u16*)d_in[2],
        (const u16*)d_in[3], (const u16*)d_in[4], (const u16*)d_in[5],
        (const u16*)d_in[6], (const u16*)d_in[7], (const u16*)d_in[8],
        (const u16*)d_in[9], (const u16*)d_in[10], (const u16*)d_in[11],
        (const u16*)d_in[12],
        in_sizes[0], in_sizes[1], in_sizes[2], in_sizes[3], in_sizes[4],
        in_sizes[5], in_sizes[6], in_sizes[7], in_sizes[8], in_sizes[9],
        in_sizes[10], in_sizes[11], in_sizes[12], flags);

    convert_kernel<<<657, 256, 0, stream>>>(
        d_in[2], d_in[9], d_in[7], d_in[1], d_in[3], d_in[4], d_in[5],
        d_in[6], d_in[8], d_in[10], d_in[11], d_in[12], (u16*)W, flags);

    qcos_kernel<<<8192, 256, 0, stream>>>(d_in[0], wTa, q, flags);

    gemm_bias_res<<<dim3(256, 4), 256, 0, stream>>>(
        q, wWc, wBc, d_in[0], y1, 512, 512, flags);        // res = x, dtype per flags[0]

    for (int c = 0; c < 4; c++) {
        size_t off = (size_t)c * 8192 * 512;
        ln1_ffn1_kernel<<<8192, 256, 0, stream>>>(
            y1 + off, wG1, wB1l, wTf, wW1, wB1, x1 + off, hb);
        gemm_bias_res<<<dim3(64, 4), 256, 0, stream>>>(
            hb, wW2, wB2, x1 + off, z + off, 2048, 512, flags + 15);  // res = x1 (bf16)
    }

    ln2_kernel<<<32768, 256, 0, stream>>>(z, wG2, wB2l, d_out, flags);
}

// Round 3
// 409.953 us; speedup vs baseline: 1.5299x; 1.5299x over previous
//
#include <hip/hip_runtime.h>
#include <stdint.h>

typedef unsigned short u16;
typedef __bf16 bf16x8 __attribute__((ext_vector_type(8)));
typedef float f32x4 __attribute__((ext_vector_type(4)));

#define AS1(p) ((const __attribute__((address_space(1))) void*)(p))
#define AS3(p) ((__attribute__((address_space(3))) void*)(p))

__device__ __forceinline__ float b2f(u16 v){
    union { unsigned u; float f; } x; x.u = ((unsigned)v) << 16; return x.f;
}
__device__ __forceinline__ u16 f2b(float f){
    union { float f; unsigned u; } x; x.f = f;
    unsigned r = x.u + 0x7FFFu + ((x.u >> 16) & 1u);
    return (u16)(r >> 16);
}

// ---------------- dtype probe: one block per input tensor ----------------
__global__ __launch_bounds__(256) void probe_kernel(
    const u16* p0,const u16* p1,const u16* p2,const u16* p3,const u16* p4,
    const u16* p5,const u16* p6,const u16* p7,const u16* p8,const u16* p9,
    const u16* p10,const u16* p11,const u16* p12,
    int n0,int n1,int n2,int n3,int n4,int n5,int n6,int n7,int n8,int n9,
    int n10,int n11,int n12, int* flags)
{
    const u16* p; int n;
    switch (blockIdx.x) {
        case 0: p=p0; n=n0; break;   case 1: p=p1; n=n1; break;
        case 2: p=p2; n=n2; break;   case 3: p=p3; n=n3; break;
        case 4: p=p4; n=n4; break;   case 5: p=p5; n=n5; break;
        case 6: p=p6; n=n6; break;   case 7: p=p7; n=n7; break;
        case 8: p=p8; n=n8; break;   case 9: p=p9; n=n9; break;
        case 10: p=p10; n=n10; break; case 11: p=p11; n=n11; break;
        default: p=p12; n=n12; break;
    }
    int pairs = n >> 1; if (pairs > 2048) pairs = 2048;
    int strong = 0, znz = 0, tot = 0;
    for (int k = threadIdx.x; k < pairs; k += 256) {
        u16 lo = p[2*k], hi = p[2*k+1];
        int eh = (hi >> 7) & 0xFF;
        int el = (lo >> 7) & 0xFF;
        if (eh >= 0xF0 || (eh >= 1 && eh <= 0x40)) strong = 1;
        if (el >= 0xF0 || (el >= 1 && el <= 0x40)) strong = 1;
        if (lo == 0 && hi != 0) znz++;
        tot++;
    }
    __shared__ int ss, sz, st;
    if (threadIdx.x == 0) { ss = 0; sz = 0; st = 0; }
    __syncthreads();
    if (strong) atomicOr(&ss, 1);
    if (znz) atomicAdd(&sz, znz);
    atomicAdd(&st, tot);
    __syncthreads();
    if (threadIdx.x == 0) {
        flags[blockIdx.x] = (ss || (2 * sz > st)) ? 1 : 0;
        if (blockIdx.x == 0) flags[15] = 0;
    }
}

// ---------------- convert weight/vector tensors to bf16 (Tf -> f32) in ws ----------------
__global__ __launch_bounds__(256) void convert_kernel(
    const void* sWc, const void* sW2, const void* sW1,
    const void* sTa, const void* sBc, const void* sG1, const void* sB1l,
    const void* sTf, const void* sB1, const void* sB2, const void* sG2, const void* sB2l,
    u16* wbase, const int* flags)
{
    int b = blockIdx.x;
    const void* src; u16* dst; int n, fi, lb, tof32 = 0;
    if (b < 128)      { src=sWc; dst=wbase;          n=262144;  fi=2;  lb=b; }
    else if (b < 640) { src=sW2; dst=wbase+262144;   n=1048576; fi=9;  lb=b-128; }
    else if (b >= 643 && b < 651) { src=sW1; dst=wbase+1312256; n=16384; fi=7; lb=b-643; }
    else {
        lb = 0;
        switch (b) {
            case 640: src=sTa;  dst=wbase+1310720; n=512;  fi=1;  break;
            case 641: src=sBc;  dst=wbase+1311232; n=512;  fi=3;  break;
            case 642: src=sB2;  dst=wbase+1311744; n=512;  fi=10; break;
            case 651: src=sB1;  dst=wbase+1328640; n=2048; fi=8;  break;
            case 652: src=sG1;  dst=wbase+1330688; n=512;  fi=4;  break;
            case 653: src=sB1l; dst=wbase+1331200; n=512;  fi=5;  break;
            case 654: src=sG2;  dst=wbase+1331712; n=512;  fi=11; break;
            case 655: src=sB2l; dst=wbase+1332224; n=512;  fi=12; break;
            default:  src=sTf;  dst=wbase+1332736; n=8;    fi=6;  tof32=1; break;
        }
    }
    int i = lb * 256 + threadIdx.x;
    if (i * 8 >= n) return;
    if (tof32) {
        float* fd = (float*)dst;
        if (flags[fi]) {
            const float4* s = (const float4*)src;
            ((float4*)fd)[i*2] = s[i*2]; ((float4*)fd)[i*2+1] = s[i*2+1];
        } else {
            union { uint4 v; u16 h[8]; } sb;
            sb.v = ((const uint4*)src)[i];
            #pragma unroll
            for (int j = 0; j < 8; j++) fd[i*8+j] = b2f(sb.h[j]);
        }
        return;
    }
    if (flags[fi]) {
        const float4* s = (const float4*)src;
        float4 a = s[i*2], c = s[i*2+1];
        union { uint4 v; u16 h[8]; } o;
        o.h[0]=f2b(a.x); o.h[1]=f2b(a.y); o.h[2]=f2b(a.z); o.h[3]=f2b(a.w);
        o.h[4]=f2b(c.x); o.h[5]=f2b(c.y); o.h[6]=f2b(c.z); o.h[7]=f2b(c.w);
        ((uint4*)dst)[i] = o.v;
    } else {
        ((uint4*)dst)[i] = ((const uint4*)src)[i];
    }
}

// ---------------- q[m,e] = cos(x[m,e] + theta_flat[e]) ----------------
__global__ __launch_bounds__(256) void qcos_kernel(const void* x,
        const u16* __restrict__ theta, u16* __restrict__ q, const int* flags)
{
    int i = blockIdx.x * 256 + threadIdx.x;
    float xv[8];
    if (flags[0]) {
        const float4* xf = (const float4*)x;
        float4 a = xf[i*2], c = xf[i*2+1];
        xv[0]=a.x; xv[1]=a.y; xv[2]=a.z; xv[3]=a.w;
        xv[4]=c.x; xv[5]=c.y; xv[6]=c.z; xv[7]=c.w;
    } else {
        union { uint4 v; u16 h[8]; } xb;
        xb.v = ((const uint4*)x)[i];
        #pragma unroll
        for (int j = 0; j < 8; j++) xv[j] = b2f(xb.h[j]);
    }
    union { uint4 v; u16 h[8]; } tb, ob;
    tb.v = *(const uint4*)(theta + ((i * 8) & 511));
    #pragma unroll
    for (int j = 0; j < 8; j++)
        ob.h[j] = f2b(__cosf(xv[j] + b2f(tb.h[j])));
    ((uint4*)q)[i] = ob.v;
}

// ------- GEMM: dst[m,n] = sum_k A[m,k]*Wt[n,k] + bias[n] + res[m,n] -------
// XOR-swizzled LDS: stage lane->colgrp (lane&7)^(lane>>3); read slot g0^(row&7).
// Max 2-way bank aliasing (free). 128x128 tile, BK=64, global_load_lds w=16.
__global__ __launch_bounds__(256) void gemm_bias_res(
    const u16* __restrict__ A, const u16* __restrict__ Wt,
    const u16* __restrict__ bias, const void* __restrict__ res,
    u16* __restrict__ dst, int K, int N, const int* rflag)
{
    __shared__ __align__(16) u16 As[128 * 64];
    __shared__ __align__(16) u16 Bs[128 * 64];
    const int tid  = threadIdx.x;
    const int lane = tid & 63;
    const int w    = tid >> 6;
    const int m0 = blockIdx.x * 128;
    const int n0 = blockIdx.y * 128;
    const int srow = lane >> 3;
    const int scol = ((lane & 7) ^ srow) * 8;   // XOR swizzle on staging source col
    const int wm = (w >> 1) * 64;
    const int wn = (w & 1) * 64;
    const int fr   = lane & 15;
    const int quad = lane >> 4;
    const int fx   = fr & 7;                    // XOR term for fragment reads

    f32x4 acc[4][4];
    #pragma unroll
    for (int i = 0; i < 4; i++)
        #pragma unroll
        for (int j = 0; j < 4; j++)
            acc[i][j] = f32x4{0.f, 0.f, 0.f, 0.f};

    for (int kt = 0; kt < K; kt += 64) {
        __syncthreads();
        #pragma unroll
        for (int i = 0; i < 4; i++) {
            int c = w * 4 + i;
            int row = c * 8 + srow;
            __builtin_amdgcn_global_load_lds(
                AS1(A + (size_t)(m0 + row) * K + kt + scol),
                AS3(As + c * 512), 16, 0, 0);
        }
        #pragma unroll
        for (int i = 0; i < 4; i++) {
            int c = w * 4 + i;
            int row = c * 8 + srow;
            __builtin_amdgcn_global_load_lds(
                AS1(Wt + (size_t)(n0 + row) * K + kt + scol),
                AS3(Bs + c * 512), 16, 0, 0);
        }
        __syncthreads();
        #pragma unroll
        for (int kk = 0; kk < 2; kk++) {
            bf16x8 af[4], bfr[4];
            #pragma unroll
            for (int mi = 0; mi < 4; mi++)
                af[mi] = *(const bf16x8*)(As + (wm + mi * 16 + fr) * 64 +
                                          (((kk * 4 + quad) ^ fx) * 8));
            #pragma unroll
            for (int ni = 0; ni < 4; ni++)
                bfr[ni] = *(const bf16x8*)(Bs + (wn + ni * 16 + fr) * 64 +
                                           (((kk * 4 + quad) ^ fx) * 8));
            #pragma unroll
            for (int mi = 0; mi < 4; mi++)
                #pragma unroll
                for (int ni = 0; ni < 4; ni++)
                    acc[mi][ni] = __builtin_amdgcn_mfma_f32_16x16x32_bf16(
                        af[mi], bfr[ni], acc[mi][ni], 0, 0, 0);
        }
    }

    const int rf = rflag[0];
    #pragma unroll
    for (int mi = 0; mi < 4; mi++) {
        #pragma unroll
        for (int ni = 0; ni < 4; ni++) {
            int n = n0 + wn + ni * 16 + fr;
            float bn = b2f(bias[n]);
            #pragma unroll
            for (int r = 0; r < 4; r++) {
                int m = m0 + wm + mi * 16 + quad * 4 + r;
                float rv = rf ? ((const float*)res)[(size_t)m * N + n]
                              : b2f(((const u16*)res)[(size_t)m * N + n]);
                dst[(size_t)m * N + n] = f2b(acc[mi][ni][r] + bn + rv);
            }
        }
    }
}

// ------- ln1+ffn1: 512 threads, 64 rows/block. LN per-wave (8 rows each),
//         fq to LDS, W1 in registers (4 cols x 8 k per thread), h coalesced. -------
__global__ __launch_bounds__(512) void ln1_ffn1_kernel(
    const u16* __restrict__ y1, const u16* __restrict__ g, const u16* __restrict__ b,
    const float* __restrict__ tf, const u16* __restrict__ W1, const u16* __restrict__ b1,
    u16* __restrict__ x1, u16* __restrict__ h)
{
    __shared__ __align__(16) float xs8[64][8];
    __shared__ __align__(16) float fqs[64][8];
    const int t = threadIdx.x;
    const int wv = t >> 6, l = t & 63;
    const size_t rbase = (size_t)blockIdx.x * 64;

    union { uint4 v; u16 s[8]; } gb, bb;
    gb.v = *(const uint4*)(g + l * 8);
    bb.v = *(const uint4*)(b + l * 8);

    #pragma unroll
    for (int i = 0; i < 8; i++) {
        int lr = wv * 8 + i;
        union { uint4 v; u16 s[8]; } yb;
        yb.v = ((const uint4*)(y1 + (rbase + lr) * 512))[l];
        float xv[8], s = 0.f, ss = 0.f;
        #pragma unroll
        for (int j = 0; j < 8; j++) {
            xv[j] = b2f(yb.s[j]); s += xv[j]; ss += xv[j] * xv[j];
        }
        #pragma unroll
        for (int o = 32; o > 0; o >>= 1) { s += __shfl_down(s, o); ss += __shfl_down(ss, o); }
        s = __shfl(s, 0); ss = __shfl(ss, 0);
        float mu = s * (1.f / 512.f);
        float rs = rsqrtf(ss * (1.f / 512.f) - mu * mu + 1e-5f);
        union { uint4 v; u16 s[8]; } ob;
        float xn[8];
        #pragma unroll
        for (int j = 0; j < 8; j++) {
            xn[j] = (xv[j] - mu) * rs * b2f(gb.s[j]) + b2f(bb.s[j]);
            ob.s[j] = f2b(xn[j]);
        }
        ((uint4*)(x1 + (rbase + lr) * 512))[l] = ob.v;
        if (l == 0) {
            #pragma unroll
            for (int j = 0; j < 8; j++) xs8[lr][j] = xn[j];
        }
    }
    __syncthreads();
    { int r = t >> 3, j = t & 7; fqs[r][j] = __cosf(xs8[r][j] + tf[j]); }
    __syncthreads();

    // W1 into registers: thread owns cols [t*4, t*4+4)
    float w1r[4][8], b1r[4];
    const int c0 = t * 4;
    #pragma unroll
    for (int c = 0; c < 4; c++) {
        union { uint4 v; u16 s[8]; } wb;
        wb.v = *(const uint4*)(W1 + (c0 + c) * 8);
        #pragma unroll
        for (int k = 0; k < 8; k++) w1r[c][k] = b2f(wb.s[k]);
        b1r[c] = b2f(b1[c0 + c]);
    }
    for (int r = 0; r < 64; r++) {
        float4 fa = *(const float4*)&fqs[r][0];
        float4 fb = *(const float4*)&fqs[r][4];
        uint2 o;
        float a[4];
        #pragma unroll
        for (int c = 0; c < 4; c++) {
            float v = b1r[c];
            v += fa.x * w1r[c][0]; v += fa.y * w1r[c][1];
            v += fa.z * w1r[c][2]; v += fa.w * w1r[c][3];
            v += fb.x * w1r[c][4]; v += fb.y * w1r[c][5];
            v += fb.z * w1r[c][6]; v += fb.w * w1r[c][7];
            a[c] = fmaxf(v, 0.f);
        }
        o.x = (unsigned)f2b(a[0]) | ((unsigned)f2b(a[1]) << 16);
        o.y = (unsigned)f2b(a[2]) | ((unsigned)f2b(a[3]) << 16);
        *(uint2*)(h + (rbase + r) * 2048 + c0) = o;
    }
}

// ---------------- ln2: 1 row per wave, output dtype per flags[0] ----------------
__global__ __launch_bounds__(256) void ln2_kernel(
    const u16* __restrict__ z, const u16* __restrict__ g, const u16* __restrict__ b,
    void* __restrict__ out, const int* flags)
{
    const int t = threadIdx.x;
    const int wv = t >> 6, l = t & 63;
    const size_t row = (size_t)blockIdx.x * 4 + wv;

    union { uint4 v; u16 s[8]; } zb, gb, bb;
    zb.v = ((const uint4*)(z + row * 512))[l];
    gb.v = *(const uint4*)(g + l * 8);
    bb.v = *(const uint4*)(b + l * 8);
    float xv[8], s = 0.f, ss = 0.f;
    #pragma unroll
    for (int j = 0; j < 8; j++) { xv[j] = b2f(zb.s[j]); s += xv[j]; ss += xv[j]*xv[j]; }
    #pragma unroll
    for (int o = 32; o > 0; o >>= 1) { s += __shfl_down(s, o); ss += __shfl_down(ss, o); }
    s = __shfl(s, 0); ss = __shfl(ss, 0);
    float mu = s * (1.f / 512.f);
    float rs = rsqrtf(ss * (1.f / 512.f) - mu * mu + 1e-5f);
    float xn[8];
    #pragma unroll
    for (int j = 0; j < 8; j++)
        xn[j] = (xv[j] - mu) * rs * b2f(gb.s[j]) + b2f(bb.s[j]);
    if (flags[0]) {
        float* po = (float*)out + row * 512 + l * 8;
        float4 o0{xn[0],xn[1],xn[2],xn[3]}, o1{xn[4],xn[5],xn[6],xn[7]};
        *(float4*)po = o0; *(float4*)(po + 4) = o1;
    } else {
        union { uint4 v; u16 s[8]; } ob;
        #pragma unroll
        for (int j = 0; j < 8; j++) ob.s[j] = f2b(xn[j]);
        ((uint4*)((u16*)out + row * 512))[l] = ob.v;
    }
}

extern "C" void kernel_launch(void* const* d_in, const int* in_sizes, int n_in,
                              void* d_out, int out_size, void* d_ws, size_t ws_size,
                              hipStream_t stream)
{
    u16* ws16 = (u16*)d_ws;
    // ws layout (u16 elems):
    //   W region   [0, 1332752): converted weights (bf16; tf f32)
    //   flags      @ 1332752 (16 ints)
    //   q / x1     [1332800, 18110016)
    //   y1 / z     [18110016, 34887232)
    //   h          [34887232, +chunk_rows*2048)
    // quarter-variant total = 51664448 u16 = 103.33 MB (== round-2 proven footprint)
    u16* W     = ws16;
    int* flags = (int*)(ws16 + 1332752);
    u16* q   = ws16 + 1332800;      // also x1 (q dead after gemm1)
    u16* x1  = q;
    u16* y1  = ws16 + 18110016;     // also z (y1 rows dead after ln1_ffn1)
    u16* z   = y1;
    u16* h   = ws16 + 34887232;

    const u16*  wWc  = W;
    const u16*  wW2  = W + 262144;
    const u16*  wTa  = W + 1310720;
    const u16*  wBc  = W + 1311232;
    const u16*  wB2  = W + 1311744;
    const u16*  wW1  = W + 1312256;
    const u16*  wB1  = W + 1328640;
    const u16*  wG1  = W + 1330688;
    const u16*  wB1l = W + 1331200;
    const u16*  wG2  = W + 1331712;
    const u16*  wB2l = W + 1332224;
    const float* wTf = (const float*)(W + 1332736);

    // pick FFN chunking from ws_size (bytes): full 204.0MB / half 136.9MB / quarter 103.33MB
    int nchunks; size_t crows;
    if      (ws_size >= 203992192ull) { nchunks = 1; crows = 32768; }
    else if (ws_size >= 136883328ull) { nchunks = 2; crows = 16384; }
    else                              { nchunks = 4; crows = 8192;  }

    probe_kernel<<<13, 256, 0, stream>>>(
        (const u16*)d_in[0], (const u16*)d_in[1], (const u16*)d_in[2],
        (const u16*)d_in[3], (const u16*)d_in[4], (const u16*)d_in[5],
        (const u16*)d_in[6], (const u16*)d_in[7], (const u16*)d_in[8],
        (const u16*)d_in[9], (const u16*)d_in[10], (const u16*)d_in[11],
        (const u16*)d_in[12],
        in_sizes[0], in_sizes[1], in_sizes[2], in_sizes[3], in_sizes[4],
        in_sizes[5], in_sizes[6], in_sizes[7], in_sizes[8], in_sizes[9],
        in_sizes[10], in_sizes[11], in_sizes[12], flags);

    convert_kernel<<<657, 256, 0, stream>>>(
        d_in[2], d_in[9], d_in[7], d_in[1], d_in[3], d_in[4], d_in[5],
        d_in[6], d_in[8], d_in[10], d_in[11], d_in[12], (u16*)W, flags);

    qcos_kernel<<<8192, 256, 0, stream>>>(d_in[0], wTa, q, flags);

    gemm_bias_res<<<dim3(256, 4), 256, 0, stream>>>(
        q, wWc, wBc, d_in[0], y1, 512, 512, flags);          // res = x (dtype per flag)

    for (int c = 0; c < nchunks; c++) {
        size_t off = (size_t)c * crows * 512;
        ln1_ffn1_kernel<<<crows / 64, 512, 0, stream>>>(
            y1 + off, wG1, wB1l, wTf, wW1, wB1, x1 + off, h);
        gemm_bias_res<<<dim3(crows / 128, 4), 256, 0, stream>>>(
            h, wW2, wB2, x1 + off, z + off, 2048, 512, flags + 15);  // res = x1 (bf16)
    }

    ln2_kernel<<<8192, 256, 0, stream>>>(z, wG2, wB2l, d_out, flags);
}

// Round 4
// 399.525 us; speedup vs baseline: 1.5698x; 1.0261x over previous
//
#include <hip/hip_runtime.h>
#include <stdint.h>

typedef unsigned short u16;
typedef __bf16 bf16x8 __attribute__((ext_vector_type(8)));
typedef float f32x4 __attribute__((ext_vector_type(4)));

#define AS1(p) ((const __attribute__((address_space(1))) void*)(p))
#define AS3(p) ((__attribute__((address_space(3))) void*)(p))

__device__ __forceinline__ float b2f(u16 v){
    union { unsigned u; float f; } x; x.u = ((unsigned)v) << 16; return x.f;
}
__device__ __forceinline__ u16 f2b(float f){
    union { float f; unsigned u; } x; x.f = f;
    unsigned r = x.u + 0x7FFFu + ((x.u >> 16) & 1u);
    return (u16)(r >> 16);
}

// ---------------- dtype probe: one block per input tensor ----------------
__global__ __launch_bounds__(256) void probe_kernel(
    const u16* p0,const u16* p1,const u16* p2,const u16* p3,const u16* p4,
    const u16* p5,const u16* p6,const u16* p7,const u16* p8,const u16* p9,
    const u16* p10,const u16* p11,const u16* p12,
    int n0,int n1,int n2,int n3,int n4,int n5,int n6,int n7,int n8,int n9,
    int n10,int n11,int n12, int* flags)
{
    const u16* p; int n;
    switch (blockIdx.x) {
        case 0: p=p0; n=n0; break;   case 1: p=p1; n=n1; break;
        case 2: p=p2; n=n2; break;   case 3: p=p3; n=n3; break;
        case 4: p=p4; n=n4; break;   case 5: p=p5; n=n5; break;
        case 6: p=p6; n=n6; break;   case 7: p=p7; n=n7; break;
        case 8: p=p8; n=n8; break;   case 9: p=p9; n=n9; break;
        case 10: p=p10; n=n10; break; case 11: p=p11; n=n11; break;
        default: p=p12; n=n12; break;
    }
    int pairs = n >> 1; if (pairs > 2048) pairs = 2048;
    int strong = 0, znz = 0, tot = 0;
    for (int k = threadIdx.x; k < pairs; k += 256) {
        u16 lo = p[2*k], hi = p[2*k+1];
        int eh = (hi >> 7) & 0xFF;
        int el = (lo >> 7) & 0xFF;
        if (eh >= 0xF0 || (eh >= 1 && eh <= 0x40)) strong = 1;
        if (el >= 0xF0 || (el >= 1 && el <= 0x40)) strong = 1;
        if (lo == 0 && hi != 0) znz++;
        tot++;
    }
    __shared__ int ss, sz, st;
    if (threadIdx.x == 0) { ss = 0; sz = 0; st = 0; }
    __syncthreads();
    if (strong) atomicOr(&ss, 1);
    if (znz) atomicAdd(&sz, znz);
    atomicAdd(&st, tot);
    __syncthreads();
    if (threadIdx.x == 0) {
        flags[blockIdx.x] = (ss || (2 * sz > st)) ? 1 : 0;
        if (blockIdx.x == 0) flags[15] = 0;
    }
}

// ---------------- convert weight/vector tensors to bf16 (Tf -> f32) in ws ----------------
__global__ __launch_bounds__(256) void convert_kernel(
    const void* sWc, const void* sW2, const void* sW1,
    const void* sTa, const void* sBc, const void* sG1, const void* sB1l,
    const void* sTf, const void* sB1, const void* sB2, const void* sG2, const void* sB2l,
    u16* wbase, const int* flags)
{
    int b = blockIdx.x;
    const void* src; u16* dst; int n, fi, lb, tof32 = 0;
    if (b < 128)      { src=sWc; dst=wbase;          n=262144;  fi=2;  lb=b; }
    else if (b < 640) { src=sW2; dst=wbase+262144;   n=1048576; fi=9;  lb=b-128; }
    else if (b >= 643 && b < 651) { src=sW1; dst=wbase+1312256; n=16384; fi=7; lb=b-643; }
    else {
        lb = 0;
        switch (b) {
            case 640: src=sTa;  dst=wbase+1310720; n=512;  fi=1;  break;
            case 641: src=sBc;  dst=wbase+1311232; n=512;  fi=3;  break;
            case 642: src=sB2;  dst=wbase+1311744; n=512;  fi=10; break;
            case 651: src=sB1;  dst=wbase+1328640; n=2048; fi=8;  break;
            case 652: src=sG1;  dst=wbase+1330688; n=512;  fi=4;  break;
            case 653: src=sB1l; dst=wbase+1331200; n=512;  fi=5;  break;
            case 654: src=sG2;  dst=wbase+1331712; n=512;  fi=11; break;
            case 655: src=sB2l; dst=wbase+1332224; n=512;  fi=12; break;
            default:  src=sTf;  dst=wbase+1332736; n=8;    fi=6;  tof32=1; break;
        }
    }
    int i = lb * 256 + threadIdx.x;
    if (i * 8 >= n) return;
    if (tof32) {
        float* fd = (float*)dst;
        if (flags[fi]) {
            const float4* s = (const float4*)src;
            ((float4*)fd)[i*2] = s[i*2]; ((float4*)fd)[i*2+1] = s[i*2+1];
        } else {
            union { uint4 v; u16 h[8]; } sb;
            sb.v = ((const uint4*)src)[i];
            #pragma unroll
            for (int j = 0; j < 8; j++) fd[i*8+j] = b2f(sb.h[j]);
        }
        return;
    }
    if (flags[fi]) {
        const float4* s = (const float4*)src;
        float4 a = s[i*2], c = s[i*2+1];
        union { uint4 v; u16 h[8]; } o;
        o.h[0]=f2b(a.x); o.h[1]=f2b(a.y); o.h[2]=f2b(a.z); o.h[3]=f2b(a.w);
        o.h[4]=f2b(c.x); o.h[5]=f2b(c.y); o.h[6]=f2b(c.z); o.h[7]=f2b(c.w);
        ((uint4*)dst)[i] = o.v;
    } else {
        ((uint4*)dst)[i] = ((const uint4*)src)[i];
    }
}

// ---------------- q[m,e] = cos(x[m,e] + theta_flat[e]) ----------------
__global__ __launch_bounds__(256) void qcos_kernel(const void* x,
        const u16* __restrict__ theta, u16* __restrict__ q, const int* flags)
{
    int i = blockIdx.x * 256 + threadIdx.x;
    float xv[8];
    if (flags[0]) {
        const float4* xf = (const float4*)x;
        float4 a = xf[i*2], c = xf[i*2+1];
        xv[0]=a.x; xv[1]=a.y; xv[2]=a.z; xv[3]=a.w;
        xv[4]=c.x; xv[5]=c.y; xv[6]=c.z; xv[7]=c.w;
    } else {
        union { uint4 v; u16 h[8]; } xb;
        xb.v = ((const uint4*)x)[i];
        #pragma unroll
        for (int j = 0; j < 8; j++) xv[j] = b2f(xb.h[j]);
    }
    union { uint4 v; u16 h[8]; } tb, ob;
    tb.v = *(const uint4*)(theta + ((i * 8) & 511));
    #pragma unroll
    for (int j = 0; j < 8; j++)
        ob.h[j] = f2b(__cosf(xv[j] + b2f(tb.h[j])));
    ((uint4*)q)[i] = ob.v;
}

// ------- GEMM: dst[m,n] = sum_k A[m,k]*Wt[n,k] + bias[n] + res[m,n] -------
// Double-buffered LDS (stage issued AFTER barrier -> loads age one full compute
// phase before the next barrier's vmcnt drain). XCD swizzle: the ntiles blocks
// sharing an A m-tile run on the same XCD (b&7) for L2 A reuse.
// XOR-swizzled LDS banks (0 conflicts, proven r3). 128x128 tile, BK=64.
__global__ __launch_bounds__(256) void gemm_bias_res(
    const u16* __restrict__ A, const u16* __restrict__ Wt,
    const u16* __restrict__ bias, const void* __restrict__ res,
    u16* __restrict__ dst, int K, int N, int mtiles, const int* rflag)
{
    __shared__ __align__(16) u16 As[2][128 * 64];
    __shared__ __align__(16) u16 Bs[2][128 * 64];
    const int tid  = threadIdx.x;
    const int lane = tid & 63;
    const int w    = tid >> 6;

    const int ntiles = N >> 7;                 // 4 here
    const int b   = blockIdx.x;
    const int xcd = b & 7;
    const int j   = b >> 3;
    const int per = mtiles >> 3;               // m-tiles per XCD
    const int mt  = xcd * per + j / ntiles;
    const int nt  = j % ntiles;
    const int m0 = mt * 128;
    const int n0 = nt * 128;

    const int srow = lane >> 3;
    const int scol = ((lane & 7) ^ srow) * 8;  // XOR bank swizzle (staging)
    const int wm = (w >> 1) * 64;
    const int wn = (w & 1) * 64;
    const int fr   = lane & 15;
    const int quad = lane >> 4;
    const int fx   = fr & 7;

    f32x4 acc[4][4];
    #pragma unroll
    for (int i = 0; i < 4; i++)
        #pragma unroll
        for (int jj = 0; jj < 4; jj++)
            acc[i][jj] = f32x4{0.f, 0.f, 0.f, 0.f};

    const u16* Abase = A + (size_t)m0 * K + scol;
    const u16* Bbase = Wt + (size_t)n0 * K + scol;

    // prologue: stage tile 0 into buffer 0
    #pragma unroll
    for (int i = 0; i < 4; i++) {
        int c = w * 4 + i;
        int row = c * 8 + srow;
        __builtin_amdgcn_global_load_lds(AS1(Abase + (size_t)row * K),
                                         AS3(&As[0][c * 512]), 16, 0, 0);
        __builtin_amdgcn_global_load_lds(AS1(Bbase + (size_t)row * K),
                                         AS3(&Bs[0][c * 512]), 16, 0, 0);
    }

    int cur = 0;
    for (int kt = 0; kt < K; kt += 64) {
        __syncthreads();   // drains vmcnt: buffer `cur` staged; prev reads done
        if (kt + 64 < K) { // stage next tile into other buffer (ages during compute)
            int nxt = cur ^ 1;
            #pragma unroll
            for (int i = 0; i < 4; i++) {
                int c = w * 4 + i;
                int row = c * 8 + srow;
                __builtin_amdgcn_global_load_lds(
                    AS1(Abase + (size_t)row * K + kt + 64),
                    AS3(&As[nxt][c * 512]), 16, 0, 0);
                __builtin_amdgcn_global_load_lds(
                    AS1(Bbase + (size_t)row * K + kt + 64),
                    AS3(&Bs[nxt][c * 512]), 16, 0, 0);
            }
        }
        #pragma unroll
        for (int kk = 0; kk < 2; kk++) {
            bf16x8 af[4], bfr[4];
            #pragma unroll
            for (int mi = 0; mi < 4; mi++)
                af[mi] = *(const bf16x8*)(&As[cur][(wm + mi * 16 + fr) * 64 +
                                          (((kk * 4 + quad) ^ fx) * 8)]);
            #pragma unroll
            for (int ni = 0; ni < 4; ni++)
                bfr[ni] = *(const bf16x8*)(&Bs[cur][(wn + ni * 16 + fr) * 64 +
                                           (((kk * 4 + quad) ^ fx) * 8)]);
            #pragma unroll
            for (int mi = 0; mi < 4; mi++)
                #pragma unroll
                for (int ni = 0; ni < 4; ni++)
                    acc[mi][ni] = __builtin_amdgcn_mfma_f32_16x16x32_bf16(
                        af[mi], bfr[ni], acc[mi][ni], 0, 0, 0);
        }
        cur ^= 1;
    }

    const int rf = rflag[0];
    #pragma unroll
    for (int mi = 0; mi < 4; mi++) {
        #pragma unroll
        for (int ni = 0; ni < 4; ni++) {
            int n = n0 + wn + ni * 16 + fr;
            float bn = b2f(bias[n]);
            #pragma unroll
            for (int r = 0; r < 4; r++) {
                int m = m0 + wm + mi * 16 + quad * 4 + r;
                float rv = rf ? ((const float*)res)[(size_t)m * N + n]
                              : b2f(((const u16*)res)[(size_t)m * N + n]);
                dst[(size_t)m * N + n] = f2b(acc[mi][ni][r] + bn + rv);
            }
        }
    }
}

// ------- ln1+ffn1: 512 threads, 64 rows/block. LN per-wave (8 rows each),
//         fq to LDS, W1 in registers (4 cols x 8 k per thread), h coalesced. -------
__global__ __launch_bounds__(512) void ln1_ffn1_kernel(
    const u16* __restrict__ y1, const u16* __restrict__ g, const u16* __restrict__ b,
    const float* __restrict__ tf, const u16* __restrict__ W1, const u16* __restrict__ b1,
    u16* __restrict__ x1, u16* __restrict__ h)
{
    __shared__ __align__(16) float xs8[64][8];
    __shared__ __align__(16) float fqs[64][8];
    const int t = threadIdx.x;
    const int wv = t >> 6, l = t & 63;
    const size_t rbase = (size_t)blockIdx.x * 64;

    union { uint4 v; u16 s[8]; } gb, bb;
    gb.v = *(const uint4*)(g + l * 8);
    bb.v = *(const uint4*)(b + l * 8);

    #pragma unroll
    for (int i = 0; i < 8; i++) {
        int lr = wv * 8 + i;
        union { uint4 v; u16 s[8]; } yb;
        yb.v = ((const uint4*)(y1 + (rbase + lr) * 512))[l];
        float xv[8], s = 0.f, ss = 0.f;
        #pragma unroll
        for (int jj = 0; jj < 8; jj++) {
            xv[jj] = b2f(yb.s[jj]); s += xv[jj]; ss += xv[jj] * xv[jj];
        }
        #pragma unroll
        for (int o = 32; o > 0; o >>= 1) { s += __shfl_down(s, o); ss += __shfl_down(ss, o); }
        s = __shfl(s, 0); ss = __shfl(ss, 0);
        float mu = s * (1.f / 512.f);
        float rs = rsqrtf(ss * (1.f / 512.f) - mu * mu + 1e-5f);
        union { uint4 v; u16 s[8]; } ob;
        float xn[8];
        #pragma unroll
        for (int jj = 0; jj < 8; jj++) {
            xn[jj] = (xv[jj] - mu) * rs * b2f(gb.s[jj]) + b2f(bb.s[jj]);
            ob.s[jj] = f2b(xn[jj]);
        }
        ((uint4*)(x1 + (rbase + lr) * 512))[l] = ob.v;
        if (l == 0) {
            #pragma unroll
            for (int jj = 0; jj < 8; jj++) xs8[lr][jj] = xn[jj];
        }
    }
    __syncthreads();
    { int r = t >> 3, jj = t & 7; fqs[r][jj] = __cosf(xs8[r][jj] + tf[jj]); }
    __syncthreads();

    float w1r[4][8], b1r[4];
    const int c0 = t * 4;
    #pragma unroll
    for (int c = 0; c < 4; c++) {
        union { uint4 v; u16 s[8]; } wb;
        wb.v = *(const uint4*)(W1 + (c0 + c) * 8);
        #pragma unroll
        for (int k = 0; k < 8; k++) w1r[c][k] = b2f(wb.s[k]);
        b1r[c] = b2f(b1[c0 + c]);
    }
    for (int r = 0; r < 64; r++) {
        float4 fa = *(const float4*)&fqs[r][0];
        float4 fb = *(const float4*)&fqs[r][4];
        uint2 o;
        float a[4];
        #pragma unroll
        for (int c = 0; c < 4; c++) {
            float v = b1r[c];
            v += fa.x * w1r[c][0]; v += fa.y * w1r[c][1];
            v += fa.z * w1r[c][2]; v += fa.w * w1r[c][3];
            v += fb.x * w1r[c][4]; v += fb.y * w1r[c][5];
            v += fb.z * w1r[c][6]; v += fb.w * w1r[c][7];
            a[c] = fmaxf(v, 0.f);
        }
        o.x = (unsigned)f2b(a[0]) | ((unsigned)f2b(a[1]) << 16);
        o.y = (unsigned)f2b(a[2]) | ((unsigned)f2b(a[3]) << 16);
        *(uint2*)(h + (rbase + r) * 2048 + c0) = o;
    }
}

// ---------------- ln2: 1 row per wave, output dtype per flags[0] ----------------
__global__ __launch_bounds__(256) void ln2_kernel(
    const u16* __restrict__ z, const u16* __restrict__ g, const u16* __restrict__ b,
    void* __restrict__ out, const int* flags)
{
    const int t = threadIdx.x;
    const int wv = t >> 6, l = t & 63;
    const size_t row = (size_t)blockIdx.x * 4 + wv;

    union { uint4 v; u16 s[8]; } zb, gb, bb;
    zb.v = ((const uint4*)(z + row * 512))[l];
    gb.v = *(const uint4*)(g + l * 8);
    bb.v = *(const uint4*)(b + l * 8);
    float xv[8], s = 0.f, ss = 0.f;
    #pragma unroll
    for (int jj = 0; jj < 8; jj++) { xv[jj] = b2f(zb.s[jj]); s += xv[jj]; ss += xv[jj]*xv[jj]; }
    #pragma unroll
    for (int o = 32; o > 0; o >>= 1) { s += __shfl_down(s, o); ss += __shfl_down(ss, o); }
    s = __shfl(s, 0); ss = __shfl(ss, 0);
    float mu = s * (1.f / 512.f);
    float rs = rsqrtf(ss * (1.f / 512.f) - mu * mu + 1e-5f);
    float xn[8];
    #pragma unroll
    for (int jj = 0; jj < 8; jj++)
        xn[jj] = (xv[jj] - mu) * rs * b2f(gb.s[jj]) + b2f(bb.s[jj]);
    if (flags[0]) {
        float* po = (float*)out + row * 512 + l * 8;
        float4 o0{xn[0],xn[1],xn[2],xn[3]}, o1{xn[4],xn[5],xn[6],xn[7]};
        *(float4*)po = o0; *(float4*)(po + 4) = o1;
    } else {
        union { uint4 v; u16 s[8]; } ob;
        #pragma unroll
        for (int jj = 0; jj < 8; jj++) ob.s[jj] = f2b(xn[jj]);
        ((uint4*)((u16*)out + row * 512))[l] = ob.v;
    }
}

extern "C" void kernel_launch(void* const* d_in, const int* in_sizes, int n_in,
                              void* d_out, int out_size, void* d_ws, size_t ws_size,
                              hipStream_t stream)
{
    u16* ws16 = (u16*)d_ws;
    u16* W     = ws16;
    int* flags = (int*)(ws16 + 1332752);
    u16* q   = ws16 + 1332800;      // also x1 (q dead after gemm1)
    u16* x1  = q;
    u16* y1  = ws16 + 18110016;     // also z (y1 rows dead after ln1_ffn1)
    u16* z   = y1;
    u16* h   = ws16 + 34887232;

    const u16*  wWc  = W;
    const u16*  wW2  = W + 262144;
    const u16*  wTa  = W + 1310720;
    const u16*  wBc  = W + 1311232;
    const u16*  wB2  = W + 1311744;
    const u16*  wW1  = W + 1312256;
    const u16*  wB1  = W + 1328640;
    const u16*  wG1  = W + 1330688;
    const u16*  wB1l = W + 1331200;
    const u16*  wG2  = W + 1331712;
    const u16*  wB2l = W + 1332224;
    const float* wTf = (const float*)(W + 1332736);

    int nchunks; size_t crows;
    if      (ws_size >= 203992192ull) { nchunks = 1; crows = 32768; }
    else if (ws_size >= 136883328ull) { nchunks = 2; crows = 16384; }
    else                              { nchunks = 4; crows = 8192;  }

    probe_kernel<<<13, 256, 0, stream>>>(
        (const u16*)d_in[0], (const u16*)d_in[1], (const u16*)d_in[2],
        (const u16*)d_in[3], (const u16*)d_in[4], (const u16*)d_in[5],
        (const u16*)d_in[6], (const u16*)d_in[7], (const u16*)d_in[8],
        (const u16*)d_in[9], (const u16*)d_in[10], (const u16*)d_in[11],
        (const u16*)d_in[12],
        in_sizes[0], in_sizes[1], in_sizes[2], in_sizes[3], in_sizes[4],
        in_sizes[5], in_sizes[6], in_sizes[7], in_sizes[8], in_sizes[9],
        in_sizes[10], in_sizes[11], in_sizes[12], flags);

    convert_kernel<<<657, 256, 0, stream>>>(
        d_in[2], d_in[9], d_in[7], d_in[1], d_in[3], d_in[4], d_in[5],
        d_in[6], d_in[8], d_in[10], d_in[11], d_in[12], (u16*)W, flags);

    qcos_kernel<<<8192, 256, 0, stream>>>(d_in[0], wTa, q, flags);

    gemm_bias_res<<<1024, 256, 0, stream>>>(
        q, wWc, wBc, d_in[0], y1, 512, 512, 256, flags);     // res = x (dtype per flag)

    for (int c = 0; c < nchunks; c++) {
        size_t off = (size_t)c * crows * 512;
        ln1_ffn1_kernel<<<crows / 64, 512, 0, stream>>>(
            y1 + off, wG1, wB1l, wTf, wW1, wB1, x1 + off, h);
        gemm_bias_res<<<(int)(crows / 128) * 4, 256, 0, stream>>>(
            h, wW2, wB2, x1 + off, z + off, 2048, 512, (int)(crows / 128), flags + 15);
    }

    ln2_kernel<<<8192, 256, 0, stream>>>(z, wG2, wB2l, d_out, flags);
}

// Round 5
// 349.942 us; speedup vs baseline: 1.7923x; 1.1417x over previous
//
#include <hip/hip_runtime.h>
#include <stdint.h>

typedef unsigned short u16;
typedef __bf16 bf16x8 __attribute__((ext_vector_type(8)));
typedef float f32x4 __attribute__((ext_vector_type(4)));

#define AS1(p) ((const __attribute__((address_space(1))) void*)(p))
#define AS3(p) ((__attribute__((address_space(3))) void*)(p))

__device__ __forceinline__ float b2f(u16 v){
    union { unsigned u; float f; } x; x.u = ((unsigned)v) << 16; return x.f;
}
__device__ __forceinline__ u16 f2b(float f){
    union { float f; unsigned u; } x; x.f = f;
    unsigned r = x.u + 0x7FFFu + ((x.u >> 16) & 1u);
    return (u16)(r >> 16);
}

// ---------------- dtype probe: one block per input tensor (unchanged, proven) ----------------
__global__ __launch_bounds__(256) void probe_kernel(
    const u16* p0,const u16* p1,const u16* p2,const u16* p3,const u16* p4,
    const u16* p5,const u16* p6,const u16* p7,const u16* p8,const u16* p9,
    const u16* p10,const u16* p11,const u16* p12,
    int n0,int n1,int n2,int n3,int n4,int n5,int n6,int n7,int n8,int n9,
    int n10,int n11,int n12, int* flags)
{
    const u16* p; int n;
    switch (blockIdx.x) {
        case 0: p=p0; n=n0; break;   case 1: p=p1; n=n1; break;
        case 2: p=p2; n=n2; break;   case 3: p=p3; n=n3; break;
        case 4: p=p4; n=n4; break;   case 5: p=p5; n=n5; break;
        case 6: p=p6; n=n6; break;   case 7: p=p7; n=n7; break;
        case 8: p=p8; n=n8; break;   case 9: p=p9; n=n9; break;
        case 10: p=p10; n=n10; break; case 11: p=p11; n=n11; break;
        default: p=p12; n=n12; break;
    }
    int pairs = n >> 1; if (pairs > 2048) pairs = 2048;
    int strong = 0, znz = 0, tot = 0;
    for (int k = threadIdx.x; k < pairs; k += 256) {
        u16 lo = p[2*k], hi = p[2*k+1];
        int eh = (hi >> 7) & 0xFF;
        int el = (lo >> 7) & 0xFF;
        if (eh >= 0xF0 || (eh >= 1 && eh <= 0x40)) strong = 1;
        if (el >= 0xF0 || (el >= 1 && el <= 0x40)) strong = 1;
        if (lo == 0 && hi != 0) znz++;
        tot++;
    }
    __shared__ int ss, sz, st;
    if (threadIdx.x == 0) { ss = 0; sz = 0; st = 0; }
    __syncthreads();
    if (strong) atomicOr(&ss, 1);
    if (znz) atomicAdd(&sz, znz);
    atomicAdd(&st, tot);
    __syncthreads();
    if (threadIdx.x == 0) {
        flags[blockIdx.x] = (ss || (2 * sz > st)) ? 1 : 0;
        if (blockIdx.x == 0) flags[15] = 0;
    }
}

// ---------------- convert weight/vector tensors to bf16 (Tf -> f32) in ws (unchanged) -----------
__global__ __launch_bounds__(256) void convert_kernel(
    const void* sWc, const void* sW2, const void* sW1,
    const void* sTa, const void* sBc, const void* sG1, const void* sB1l,
    const void* sTf, const void* sB1, const void* sB2, const void* sG2, const void* sB2l,
    u16* wbase, const int* flags)
{
    int b = blockIdx.x;
    const void* src; u16* dst; int n, fi, lb, tof32 = 0;
    if (b < 128)      { src=sWc; dst=wbase;          n=262144;  fi=2;  lb=b; }
    else if (b < 640) { src=sW2; dst=wbase+262144;   n=1048576; fi=9;  lb=b-128; }
    else if (b >= 643 && b < 651) { src=sW1; dst=wbase+1312256; n=16384; fi=7; lb=b-643; }
    else {
        lb = 0;
        switch (b) {
            case 640: src=sTa;  dst=wbase+1310720; n=512;  fi=1;  break;
            case 641: src=sBc;  dst=wbase+1311232; n=512;  fi=3;  break;
            case 642: src=sB2;  dst=wbase+1311744; n=512;  fi=10; break;
            case 651: src=sB1;  dst=wbase+1328640; n=2048; fi=8;  break;
            case 652: src=sG1;  dst=wbase+1330688; n=512;  fi=4;  break;
            case 653: src=sB1l; dst=wbase+1331200; n=512;  fi=5;  break;
            case 654: src=sG2;  dst=wbase+1331712; n=512;  fi=11; break;
            case 655: src=sB2l; dst=wbase+1332224; n=512;  fi=12; break;
            default:  src=sTf;  dst=wbase+1332736; n=8;    fi=6;  tof32=1; break;
        }
    }
    int i = lb * 256 + threadIdx.x;
    if (i * 8 >= n) return;
    if (tof32) {
        float* fd = (float*)dst;
        if (flags[fi]) {
            const float4* s = (const float4*)src;
            ((float4*)fd)[i*2] = s[i*2]; ((float4*)fd)[i*2+1] = s[i*2+1];
        } else {
            union { uint4 v; u16 h[8]; } sb;
            sb.v = ((const uint4*)src)[i];
            #pragma unroll
            for (int j = 0; j < 8; j++) fd[i*8+j] = b2f(sb.h[j]);
        }
        return;
    }
    if (flags[fi]) {
        const float4* s = (const float4*)src;
        float4 a = s[i*2], c = s[i*2+1];
        union { uint4 v; u16 h[8]; } o;
        o.h[0]=f2b(a.x); o.h[1]=f2b(a.y); o.h[2]=f2b(a.z); o.h[3]=f2b(a.w);
        o.h[4]=f2b(c.x); o.h[5]=f2b(c.y); o.h[6]=f2b(c.z); o.h[7]=f2b(c.w);
        ((uint4*)dst)[i] = o.v;
    } else {
        ((uint4*)dst)[i] = ((const uint4*)src)[i];
    }
}

// ======== gemm1 fused: y1[m,n] = sum_k cos(x[m,k]+th[k])*Wc[n,k] + bc[n] + x[m,n] ========
// A-tile generated in LDS each iter (x streamed to regs one iter ahead, VALU cos).
// K-loop global traffic: x stream (reg dbuf) + Wc via global_load_lds dbuf.
__global__ __launch_bounds__(256) void gemm1_fused(
    const void* __restrict__ x, const u16* __restrict__ theta,
    const u16* __restrict__ Wt, const u16* __restrict__ bias,
    u16* __restrict__ dst, int mtiles, const int* flags)
{
    __shared__ __align__(16) u16 As[128 * 64];
    __shared__ __align__(16) u16 Bs[2][128 * 64];
    __shared__ __align__(16) u16 thlds[512];
    const int K = 512, N = 512;
    const int tid  = threadIdx.x;
    const int lane = tid & 63;
    const int w    = tid >> 6;

    const int blk = blockIdx.x;
    const int xcd = blk & 7;
    const int j   = blk >> 3;
    const int per = mtiles >> 3;
    const int mt  = xcd * per + (j >> 2);
    const int nt  = j & 3;
    const int m0 = mt * 128;
    const int n0 = nt * 128;

    const int srow = lane >> 3;
    const int scol = ((lane & 7) ^ srow) * 8;
    const int wm = (w >> 1) * 64;
    const int wn = (w & 1) * 64;
    const int fr   = lane & 15;
    const int quad = lane >> 4;
    const int fx   = fr & 7;

    // cos-gen assignment: thread covers row genrow, k-cols [khalf*32, khalf*32+32)
    const int genrow = tid & 127;
    const int khalf  = tid >> 7;
    const int isf32  = flags[0];

    if (tid < 64) ((uint4*)thlds)[tid] = ((const uint4*)theta)[tid];

    f32x4 acc[4][4];
    #pragma unroll
    for (int i = 0; i < 4; i++)
        #pragma unroll
        for (int jj = 0; jj < 4; jj++)
            acc[i][jj] = f32x4{0.f, 0.f, 0.f, 0.f};

    const u16* Bbase = Wt + (size_t)n0 * K + scol;

    // prologue: stage Bs[0]; load x regs for iter 0
    #pragma unroll
    for (int i = 0; i < 4; i++) {
        int c = w * 4 + i;
        int row = c * 8 + srow;
        __builtin_amdgcn_global_load_lds(AS1(Bbase + (size_t)row * K),
                                         AS3(&Bs[0][c * 512]), 16, 0, 0);
    }
    uint4 xr[8];
    {
        size_t eoff = (size_t)(m0 + genrow) * 512 + khalf * 32;
        if (isf32) {
            const uint4* p = (const uint4*)x + (eoff >> 2);
            #pragma unroll
            for (int i = 0; i < 8; i++) xr[i] = p[i];
        } else {
            const uint4* p = (const uint4*)x + (eoff >> 3);
            #pragma unroll
            for (int i = 0; i < 4; i++) xr[i] = p[i];
        }
    }

    int cur = 0;
    for (int kt = 0; kt < K; kt += 64) {
        __syncthreads();                       // As free, Bs[cur] staged, xr loaded
        // ---- phase A: cos-gen into As ----
        {
            float xv[32];
            if (isf32) {
                const float* xf = (const float*)xr;
                #pragma unroll
                for (int i2 = 0; i2 < 32; i2++) xv[i2] = xf[i2];
            } else {
                const u16* xh = (const u16*)xr;
                #pragma unroll
                for (int i2 = 0; i2 < 32; i2++) xv[i2] = b2f(xh[i2]);
            }
            int tbase = (kt + khalf * 32) >> 3;   // uint4 index into thlds
            #pragma unroll
            for (int jj = 0; jj < 4; jj++) {
                union { uint4 v; u16 h[8]; } tb;
                tb.v = ((const uint4*)thlds)[tbase + jj];
                union { uint4 v; __bf16 h[8]; } ob;
                #pragma unroll
                for (int e = 0; e < 8; e++)
                    ob.h[e] = (__bf16)__cosf(xv[jj * 8 + e] + b2f(tb.h[e]));
                int o = khalf * 4 + jj;           // k-octet
                *(uint4*)(As + genrow * 64 + ((o ^ (genrow & 7)) * 8)) = ob.v;
            }
        }
        __syncthreads();                       // As ready
        // ---- phase B: prefetch next x + stage next Bs; main MFMA ----
        if (kt + 64 < K) {
            size_t eoff = (size_t)(m0 + genrow) * 512 + kt + 64 + khalf * 32;
            if (isf32) {
                const uint4* p = (const uint4*)x + (eoff >> 2);
                #pragma unroll
                for (int i = 0; i < 8; i++) xr[i] = p[i];
            } else {
                const uint4* p = (const uint4*)x + (eoff >> 3);
                #pragma unroll
                for (int i = 0; i < 4; i++) xr[i] = p[i];
            }
            int nxt = cur ^ 1;
            #pragma unroll
            for (int i = 0; i < 4; i++) {
                int c = w * 4 + i;
                int row = c * 8 + srow;
                __builtin_amdgcn_global_load_lds(
                    AS1(Bbase + (size_t)row * K + kt + 64),
                    AS3(&Bs[nxt][c * 512]), 16, 0, 0);
            }
        }
        #pragma unroll
        for (int kk = 0; kk < 2; kk++) {
            bf16x8 af[4], bfr[4];
            #pragma unroll
            for (int mi = 0; mi < 4; mi++)
                af[mi] = *(const bf16x8*)(As + (wm + mi * 16 + fr) * 64 +
                                          (((kk * 4 + quad) ^ fx) * 8));
            #pragma unroll
            for (int ni = 0; ni < 4; ni++)
                bfr[ni] = *(const bf16x8*)(&Bs[cur][(wn + ni * 16 + fr) * 64 +
                                           (((kk * 4 + quad) ^ fx) * 8)]);
            #pragma unroll
            for (int mi = 0; mi < 4; mi++)
                #pragma unroll
                for (int ni = 0; ni < 4; ni++)
                    acc[mi][ni] = __builtin_amdgcn_mfma_f32_16x16x32_bf16(
                        af[mi], bfr[ni], acc[mi][ni], 0, 0, 0);
        }
        cur ^= 1;
    }

    #pragma unroll
    for (int mi = 0; mi < 4; mi++) {
        #pragma unroll
        for (int ni = 0; ni < 4; ni++) {
            int n = n0 + wn + ni * 16 + fr;
            float bn = b2f(bias[n]);
            #pragma unroll
            for (int r = 0; r < 4; r++) {
                int m = m0 + wm + mi * 16 + quad * 4 + r;
                float rv = isf32 ? ((const float*)x)[(size_t)m * N + n]
                                 : b2f(((const u16*)x)[(size_t)m * N + n]);
                dst[(size_t)m * N + n] = f2b(acc[mi][ni][r] + bn + rv);
            }
        }
    }
}

// ======== gemm2 fused: z[m,n] = sum_k relu(fq[m,:8]@W1[k,:8]+b1[k])*W2[n,k] + b2[n] + x1[m,n] ====
// h-tile generated in LDS each iter by a swapped-operand padded-K MFMA:
//   h^T-slice[f][m] = sum_q W1[kt+f][q]*fq[m][q]  (C preloaded with b1) -> relu -> ds_write_b64.
// K-loop global traffic: W2 only (L2-resident) + tiny W1/b1 reg prefetches.
__global__ __launch_bounds__(256) void gemm2_fused(
    const u16* __restrict__ fq, const u16* __restrict__ W1, const u16* __restrict__ b1,
    const u16* __restrict__ Wt, const u16* __restrict__ bias,
    const u16* __restrict__ res, u16* __restrict__ dst, int mtiles)
{
    __shared__ __align__(16) u16 As[128 * 64];
    __shared__ __align__(16) u16 Bs[2][128 * 64];
    const int K = 2048, N = 512;
    const int tid  = threadIdx.x;
    const int lane = tid & 63;
    const int w    = tid >> 6;

    const int blk = blockIdx.x;
    const int xcd = blk & 7;
    const int j   = blk >> 3;
    const int per = mtiles >> 3;
    const int mt  = xcd * per + (j >> 2);
    const int nt  = j & 3;
    const int m0 = mt * 128;
    const int n0 = nt * 128;

    const int srow = lane >> 3;
    const int scol = ((lane & 7) ^ srow) * 8;
    const int wm = (w >> 1) * 64;
    const int wn = (w & 1) * 64;
    const int fr   = lane & 15;
    const int quad = lane >> 4;
    const int fx   = fr & 7;

    // fq B-frags: one per m-tile (16 rows), constant over K. quad0 lanes hold data.
    bf16x8 fqf[8];
    #pragma unroll
    for (int t2 = 0; t2 < 8; t2++) {
        union { uint4 v; bf16x8 b; } z; z.v = uint4{0,0,0,0};
        if (quad == 0) z.v = *(const uint4*)(fq + (size_t)(m0 + t2 * 16 + fr) * 8);
        fqf[t2] = z.b;
    }
    // W1 frag + b1 for iter 0
    union { uint4 v; bf16x8 b; } w1u; w1u.v = uint4{0,0,0,0};
    if (quad == 0) w1u.v = *(const uint4*)(W1 + (size_t)(w * 16 + fr) * 8);
    uint2 b1v = *(const uint2*)(b1 + w * 16 + quad * 4);

    f32x4 acc[4][4];
    #pragma unroll
    for (int i = 0; i < 4; i++)
        #pragma unroll
        for (int jj = 0; jj < 4; jj++)
            acc[i][jj] = f32x4{0.f, 0.f, 0.f, 0.f};

    const u16* Bbase = Wt + (size_t)n0 * K + scol;
    #pragma unroll
    for (int i = 0; i < 4; i++) {
        int c = w * 4 + i;
        int row = c * 8 + srow;
        __builtin_amdgcn_global_load_lds(AS1(Bbase + (size_t)row * K),
                                         AS3(&Bs[0][c * 512]), 16, 0, 0);
    }

    int cur = 0;
    for (int kt = 0; kt < K; kt += 64) {
        __syncthreads();                       // As free, Bs[cur] staged, w1/b1 ready
        // ---- phase A: h-gen into As ----
        {
            const u16* pb = (const u16*)&b1v;
            f32x4 binit = {b2f(pb[0]), b2f(pb[1]), b2f(pb[2]), b2f(pb[3])};
            const int g   = w * 2 + (quad >> 1);
            const int off = (quad & 1) * 4;
            #pragma unroll
            for (int t2 = 0; t2 < 8; t2++) {
                f32x4 hv = __builtin_amdgcn_mfma_f32_16x16x32_bf16(
                    w1u.b, fqf[t2], binit, 0, 0, 0);
                union { uint2 u; __bf16 h[4]; } hw;
                hw.h[0] = (__bf16)fmaxf(hv[0], 0.f);
                hw.h[1] = (__bf16)fmaxf(hv[1], 0.f);
                hw.h[2] = (__bf16)fmaxf(hv[2], 0.f);
                hw.h[3] = (__bf16)fmaxf(hv[3], 0.f);
                int m = t2 * 16 + fr;          // As-local row
                *(uint2*)(As + m * 64 + ((g ^ (m & 7)) * 8 + off)) = hw.u;
            }
        }
        __syncthreads();                       // As ready
        // ---- phase B: prefetch next W1/b1 + stage next Bs; main MFMA ----
        if (kt + 64 < K) {
            if (quad == 0)
                w1u.v = *(const uint4*)(W1 + (size_t)(kt + 64 + w * 16 + fr) * 8);
            b1v = *(const uint2*)(b1 + kt + 64 + w * 16 + quad * 4);
            int nxt = cur ^ 1;
            #pragma unroll
            for (int i = 0; i < 4; i++) {
                int c = w * 4 + i;
                int row = c * 8 + srow;
                __builtin_amdgcn_global_load_lds(
                    AS1(Bbase + (size_t)row * K + kt + 64),
                    AS3(&Bs[nxt][c * 512]), 16, 0, 0);
            }
        }
        #pragma unroll
        for (int kk = 0; kk < 2; kk++) {
            bf16x8 af[4], bfr[4];
            #pragma unroll
            for (int mi = 0; mi < 4; mi++)
                af[mi] = *(const bf16x8*)(As + (wm + mi * 16 + fr) * 64 +
                                          (((kk * 4 + quad) ^ fx) * 8));
            #pragma unroll
            for (int ni = 0; ni < 4; ni++)
                bfr[ni] = *(const bf16x8*)(&Bs[cur][(wn + ni * 16 + fr) * 64 +
                                           (((kk * 4 + quad) ^ fx) * 8)]);
            #pragma unroll
            for (int mi = 0; mi < 4; mi++)
                #pragma unroll
                for (int ni = 0; ni < 4; ni++)
                    acc[mi][ni] = __builtin_amdgcn_mfma_f32_16x16x32_bf16(
                        af[mi], bfr[ni], acc[mi][ni], 0, 0, 0);
        }
        cur ^= 1;
    }

    #pragma unroll
    for (int mi = 0; mi < 4; mi++) {
        #pragma unroll
        for (int ni = 0; ni < 4; ni++) {
            int n = n0 + wn + ni * 16 + fr;
            float bn = b2f(bias[n]);
            #pragma unroll
            for (int r = 0; r < 4; r++) {
                int m = m0 + wm + mi * 16 + quad * 4 + r;
                float rv = b2f(res[(size_t)m * N + n]);
                dst[(size_t)m * N + n] = f2b(acc[mi][ni][r] + bn + rv);
            }
        }
    }
}

// ------- ln1: x1 = LN(y1)*g+b; fq = cos(x1[:,:8]+tf)  (h generation moved into gemm2) -------
__global__ __launch_bounds__(512) void ln1_kernel(
    const u16* __restrict__ y1, const u16* __restrict__ g, const u16* __restrict__ b,
    const float* __restrict__ tf, u16* __restrict__ x1, u16* __restrict__ fqout)
{
    __shared__ __align__(16) float xs8[64][8];
    const int t = threadIdx.x;
    const int wv = t >> 6, l = t & 63;
    const size_t rbase = (size_t)blockIdx.x * 64;

    union { uint4 v; u16 s[8]; } gb, bb;
    gb.v = *(const uint4*)(g + l * 8);
    bb.v = *(const uint4*)(b + l * 8);

    #pragma unroll
    for (int i = 0; i < 8; i++) {
        int lr = wv * 8 + i;
        union { uint4 v; u16 s[8]; } yb;
        yb.v = ((const uint4*)(y1 + (rbase + lr) * 512))[l];
        float xv[8], s = 0.f, ss = 0.f;
        #pragma unroll
        for (int jj = 0; jj < 8; jj++) {
            xv[jj] = b2f(yb.s[jj]); s += xv[jj]; ss += xv[jj] * xv[jj];
        }
        #pragma unroll
        for (int o = 32; o > 0; o >>= 1) { s += __shfl_down(s, o); ss += __shfl_down(ss, o); }
        s = __shfl(s, 0); ss = __shfl(ss, 0);
        float mu = s * (1.f / 512.f);
        float rs = rsqrtf(ss * (1.f / 512.f) - mu * mu + 1e-5f);
        union { uint4 v; u16 s[8]; } ob;
        float xn[8];
        #pragma unroll
        for (int jj = 0; jj < 8; jj++) {
            xn[jj] = (xv[jj] - mu) * rs * b2f(gb.s[jj]) + b2f(bb.s[jj]);
            ob.s[jj] = f2b(xn[jj]);
        }
        ((uint4*)(x1 + (rbase + lr) * 512))[l] = ob.v;
        if (l == 0) {
            #pragma unroll
            for (int jj = 0; jj < 8; jj++) xs8[lr][jj] = xn[jj];
        }
    }
    __syncthreads();
    {
        int r = t >> 3, jj = t & 7;
        fqout[(rbase + r) * 8 + jj] = f2b(__cosf(xs8[r][jj] + tf[jj]));
    }
}

// ---------------- ln2: 1 row per wave, output dtype per flags[0] ----------------
__global__ __launch_bounds__(256) void ln2_kernel(
    const u16* __restrict__ z, const u16* __restrict__ g, const u16* __restrict__ b,
    void* __restrict__ out, const int* flags)
{
    const int t = threadIdx.x;
    const int wv = t >> 6, l = t & 63;
    const size_t row = (size_t)blockIdx.x * 4 + wv;

    union { uint4 v; u16 s[8]; } zb, gb, bb;
    zb.v = ((const uint4*)(z + row * 512))[l];
    gb.v = *(const uint4*)(g + l * 8);
    bb.v = *(const uint4*)(b + l * 8);
    float xv[8], s = 0.f, ss = 0.f;
    #pragma unroll
    for (int jj = 0; jj < 8; jj++) { xv[jj] = b2f(zb.s[jj]); s += xv[jj]; ss += xv[jj]*xv[jj]; }
    #pragma unroll
    for (int o = 32; o > 0; o >>= 1) { s += __shfl_down(s, o); ss += __shfl_down(ss, o); }
    s = __shfl(s, 0); ss = __shfl(ss, 0);
    float mu = s * (1.f / 512.f);
    float rs = rsqrtf(ss * (1.f / 512.f) - mu * mu + 1e-5f);
    float xn[8];
    #pragma unroll
    for (int jj = 0; jj < 8; jj++)
        xn[jj] = (xv[jj] - mu) * rs * b2f(gb.s[jj]) + b2f(bb.s[jj]);
    if (flags[0]) {
        float* po = (float*)out + row * 512 + l * 8;
        float4 o0{xn[0],xn[1],xn[2],xn[3]}, o1{xn[4],xn[5],xn[6],xn[7]};
        *(float4*)po = o0; *(float4*)(po + 4) = o1;
    } else {
        union { uint4 v; u16 s[8]; } ob;
        #pragma unroll
        for (int jj = 0; jj < 8; jj++) ob.s[jj] = f2b(xn[jj]);
        ((uint4*)((u16*)out + row * 512))[l] = ob.v;
    }
}

extern "C" void kernel_launch(void* const* d_in, const int* in_sizes, int n_in,
                              void* d_out, int out_size, void* d_ws, size_t ws_size,
                              hipStream_t stream)
{
    u16* ws16 = (u16*)d_ws;
    // ws (u16 elems): W [0,1332752) | flags @1332752 | fq @1332800 (262144)
    //                 x1 @1594944 (16.7M) | y1/z @18372160 (16.7M)  => ~70.3 MB total
    u16* W     = ws16;
    int* flags = (int*)(ws16 + 1332752);
    u16* fq  = ws16 + 1332800;
    u16* x1  = ws16 + 1594944;
    u16* y1  = ws16 + 18372160;
    u16* z   = y1;                  // y1 rows dead after ln1; z overwrites

    const u16*  wWc  = W;
    const u16*  wW2  = W + 262144;
    const u16*  wTa  = W + 1310720;
    const u16*  wBc  = W + 1311232;
    const u16*  wB2  = W + 1311744;
    const u16*  wW1  = W + 1312256;
    const u16*  wB1  = W + 1328640;
    const u16*  wG1  = W + 1330688;
    const u16*  wB1l = W + 1331200;
    const u16*  wG2  = W + 1331712;
    const u16*  wB2l = W + 1332224;
    const float* wTf = (const float*)(W + 1332736);

    probe_kernel<<<13, 256, 0, stream>>>(
        (const u16*)d_in[0], (const u16*)d_in[1], (const u16*)d_in[2],
        (const u16*)d_in[3], (const u16*)d_in[4], (const u16*)d_in[5],
        (const u16*)d_in[6], (const u16*)d_in[7], (const u16*)d_in[8],
        (const u16*)d_in[9], (const u16*)d_in[10], (const u16*)d_in[11],
        (const u16*)d_in[12],
        in_sizes[0], in_sizes[1], in_sizes[2], in_sizes[3], in_sizes[4],
        in_sizes[5], in_sizes[6], in_sizes[7], in_sizes[8], in_sizes[9],
        in_sizes[10], in_sizes[11], in_sizes[12], flags);

    convert_kernel<<<657, 256, 0, stream>>>(
        d_in[2], d_in[9], d_in[7], d_in[1], d_in[3], d_in[4], d_in[5],
        d_in[6], d_in[8], d_in[10], d_in[11], d_in[12], (u16*)W, flags);

    gemm1_fused<<<1024, 256, 0, stream>>>(
        d_in[0], wTa, wWc, wBc, y1, 256, flags);

    ln1_kernel<<<512, 512, 0, stream>>>(y1, wG1, wB1l, wTf, x1, fq);

    gemm2_fused<<<1024, 256, 0, stream>>>(
        fq, wW1, wB1, wW2, wB2, x1, z, 256);

    ln2_kernel<<<8192, 256, 0, stream>>>(z, wG2, wB2l, d_out, flags);
}